// Round 1
// baseline (624.922 us; speedup 1.0000x reference)
//
#include <hip/hip_runtime.h>

#define NC 10
#define PGD 10
#define ALPHA 0.15f
#define NTAB 32  // spread tables to de-contend global atomics

// ws float layout:
//   [0,    320)   counts_tab[NTAB][10]
//   [320,  32320) S_tab[PGD][NTAB][100]
//   [32320,33320) D_glob[PGD][100]   (slot i = cumulative D after i+1 steps; 0..8 written)
#define WS_COUNTS 0
#define WS_STAB   320
#define WS_DGLOB  32320
#define WS_ZERO_N 32320  // floats to zero each call

// Compute D_new = D_prev + g(S, counts) into sh_D. All threads of the block
// participate; result is bit-identical across blocks (same inputs, same order).
__device__ __forceinline__ void table_from_stats(
    const float* __restrict__ S_tab_t,    // [NTAB][100]
    const float* __restrict__ counts_tab, // [NTAB][10]
    const float* __restrict__ Dprev,      // [100] global or nullptr (== zeros)
    float* sh_D, float* sh_tmp, float* sh_cnt, float* sh_cn, int tid)
{
    if (tid < 10) {
        float s = 0.f;
        for (int k = 0; k < NTAB; ++k) s += counts_tab[k * 10 + tid];
        sh_cnt[tid] = (s == 0.f) ? 100.f : s;
    }
    if (tid < 100) {
        float s = 0.f;
        for (int k = 0; k < NTAB; ++k) s += S_tab_t[k * 100 + tid];
        sh_tmp[tid] = s;
    }
    __syncthreads();
    if (tid < 100) {
        int c = tid / 10, j = tid - c * 10;
        float g = sh_tmp[tid] / sh_cnt[c] - ((c == j) ? 1.f : 0.f);
        sh_tmp[tid] = g;
    }
    __syncthreads();
    if (tid < 10) {  // column norms: norm over rows of column `tid`
        float s = 0.f;
        for (int cc = 0; cc < 10; ++cc) { float g = sh_tmp[cc * 10 + tid]; s += g * g; }
        sh_cn[tid] = sqrtf(s);
    }
    __syncthreads();
    if (tid < 100) {
        int c = tid / 10;
        float sign = (c < 4) ? -1.f : 1.f;   // SIGN_VEC = [-1]*4 + [1]*6
        float g = sh_tmp[tid] / sh_cn[c] * (ALPHA * sign);  // row c / col_norm[c] (torch-faithful)
        sh_D[tid] = (Dprev ? Dprev[tid] : 0.f) + g;
    }
    __syncthreads();
}

__global__ void k_init(float* __restrict__ ws, float* __restrict__ out) {
    int i = blockIdx.x * blockDim.x + threadIdx.x;
    if (i == 0) out[0] = 0.f;
    int gs = gridDim.x * blockDim.x;
    for (int k = i; k < WS_ZERO_N; k += gs) ws[k] = 0.f;
}

__global__ __launch_bounds__(256) void k_step(
    const float* __restrict__ logit, const int* __restrict__ y,
    float* __restrict__ ws, int B, int t /*1..10*/, int spt)
{
    __shared__ float sh_D[100];
    __shared__ float sh_tmp[100];
    __shared__ float sh_cnt[10];
    __shared__ float sh_cn[10];
    __shared__ float wtab[4][100];
    __shared__ float ctab[4][10];
    const int tid = threadIdx.x;

    float* counts_tab = ws + WS_COUNTS;
    float* S_tab      = ws + WS_STAB;
    float* D_glob     = ws + WS_DGLOB;

    if (t >= 2) {
        const float* Dprev = (t == 2) ? nullptr : (D_glob + (size_t)(t - 3) * 100);
        table_from_stats(S_tab + (size_t)(t - 2) * (NTAB * 100), counts_tab, Dprev,
                         sh_D, sh_tmp, sh_cnt, sh_cn, tid);
        if (blockIdx.x == 0 && tid < 100) D_glob[(size_t)(t - 2) * 100 + tid] = sh_D[tid];
    }
    for (int i = tid; i < 400; i += 256) (&wtab[0][0])[i] = 0.f;
    if (t == 1) for (int i = tid; i < 40; i += 256) (&ctab[0][0])[i] = 0.f;
    __syncthreads();

    const int w = tid >> 6;
    const int gthreads = gridDim.x * blockDim.x;
    const int base = blockIdx.x * blockDim.x + tid;
    for (int k = 0; k < spt; ++k) {
        int idx = base + k * gthreads;
        if (idx >= B) break;
        int c = y[idx];
        const float2* rp = reinterpret_cast<const float2*>(logit + (size_t)idx * 10);
        float tv[10];
        #pragma unroll
        for (int q = 0; q < 5; ++q) {
            float2 v = rp[q];
            tv[2 * q] = v.x; tv[2 * q + 1] = v.y;
        }
        if (t >= 2) {
            #pragma unroll
            for (int j = 0; j < 10; ++j) tv[j] += sh_D[c * 10 + j];
        }
        float m = tv[0];
        #pragma unroll
        for (int j = 1; j < 10; ++j) m = fmaxf(m, tv[j]);
        float e[10]; float s = 0.f;
        #pragma unroll
        for (int j = 0; j < 10; ++j) { e[j] = __expf(tv[j] - m); s += e[j]; }
        float r = 1.f / s;
        #pragma unroll
        for (int j = 0; j < 10; ++j) unsafeAtomicAdd(&wtab[w][c * 10 + j], e[j] * r);
        if (t == 1) unsafeAtomicAdd(&ctab[w][c], 1.f);
    }
    __syncthreads();

    const int tb = blockIdx.x & (NTAB - 1);
    for (int i = tid; i < 100; i += 256) {
        float s4 = wtab[0][i] + wtab[1][i] + wtab[2][i] + wtab[3][i];
        unsafeAtomicAdd(&S_tab[(size_t)(t - 1) * (NTAB * 100) + tb * 100 + i], s4);
    }
    if (t == 1) {
        for (int i = tid; i < 10; i += 256) {
            float s4 = ctab[0][i] + ctab[1][i] + ctab[2][i] + ctab[3][i];
            unsafeAtomicAdd(&counts_tab[tb * 10 + i], s4);
        }
    }
}

__global__ __launch_bounds__(256) void k_final(
    const float* __restrict__ logit, const int* __restrict__ y,
    const int* __restrict__ label_freq,
    float* __restrict__ out, float* __restrict__ ws, int B, int spt)
{
    __shared__ float sh_D[100];
    __shared__ float sh_tmp[100];
    __shared__ float sh_cnt[10];
    __shared__ float sh_cn[10];
    __shared__ float Dall[PGD][100];
    __shared__ int lf[10];
    __shared__ float wsum[4];
    const int tid = threadIdx.x;

    float* counts_tab = ws + WS_COUNTS;
    float* S_tab      = ws + WS_STAB;
    float* D_glob     = ws + WS_DGLOB;

    // D_10 from S_10 + D_9
    table_from_stats(S_tab + (size_t)9 * (NTAB * 100), counts_tab, D_glob + 8 * 100,
                     sh_D, sh_tmp, sh_cnt, sh_cn, tid);
    if (tid < 100) Dall[9][tid] = sh_D[tid];
    for (int i = tid; i < 900; i += 256) Dall[i / 100][i % 100] = D_glob[i];
    if (tid < 10) lf[tid] = label_freq[tid];
    __syncthreads();

    float* news_out = out + 1;
    float* copy_out = out + 1 + (size_t)B * 10;
    const int gthreads = gridDim.x * blockDim.x;
    const int base = blockIdx.x * blockDim.x + tid;
    float acc = 0.f;
    for (int k = 0; k < spt; ++k) {
        int idx = base + k * gthreads;
        if (idx >= B) break;
        int c = y[idx];
        int sel = lf[c];  // selects state after sel+1 steps == Dall[sel]
        const float2* rp = reinterpret_cast<const float2*>(logit + (size_t)idx * 10);
        float xv[10];
        #pragma unroll
        for (int q = 0; q < 5; ++q) {
            float2 v = rp[q];
            xv[2 * q] = v.x; xv[2 * q + 1] = v.y;
        }
        float nv[10];
        #pragma unroll
        for (int j = 0; j < 10; ++j) nv[j] = xv[j] + Dall[sel][c * 10 + j];
        float2* np = reinterpret_cast<float2*>(news_out + (size_t)idx * 10);
        float2* cp = reinterpret_cast<float2*>(copy_out + (size_t)idx * 10);
        #pragma unroll
        for (int q = 0; q < 5; ++q) {
            np[q] = make_float2(nv[2 * q], nv[2 * q + 1]);
            cp[q] = make_float2(xv[2 * q], xv[2 * q + 1]);
        }
        float m = nv[0];
        #pragma unroll
        for (int j = 1; j < 10; ++j) m = fmaxf(m, nv[j]);
        float s = 0.f;
        #pragma unroll
        for (int j = 0; j < 10; ++j) s += __expf(nv[j] - m);
        float lse = __logf(s) + m;
        acc += lse - nv[c];
    }
    // wave + block reduce, one atomic per block
    #pragma unroll
    for (int off = 32; off > 0; off >>= 1) acc += __shfl_down(acc, off);
    if ((tid & 63) == 0) wsum[tid >> 6] = acc;
    __syncthreads();
    if (tid == 0) {
        float b = wsum[0] + wsum[1] + wsum[2] + wsum[3];
        unsafeAtomicAdd(out, b / (float)B);
    }
}

extern "C" void kernel_launch(void* const* d_in, const int* in_sizes, int n_in,
                              void* d_out, int out_size, void* d_ws, size_t ws_size,
                              hipStream_t stream) {
    const float* logit = (const float*)d_in[0];
    const int* y       = (const int*)d_in[1];
    const int* lf      = (const int*)d_in[2];
    float* out = (float*)d_out;
    float* ws  = (float*)d_ws;
    const int B = in_sizes[0] / 10;

    const int spt = 4;
    const int threads = 256;
    int totalThreads = (B + spt - 1) / spt;
    int blocks = (totalThreads + threads - 1) / threads;  // 1024 for B=1M

    hipLaunchKernelGGL(k_init, dim3(64), dim3(256), 0, stream, ws, out);
    for (int t = 1; t <= PGD; ++t)
        hipLaunchKernelGGL(k_step, dim3(blocks), dim3(threads), 0, stream,
                           logit, y, ws, B, t, spt);
    hipLaunchKernelGGL(k_final, dim3(blocks), dim3(threads), 0, stream,
                       logit, y, lf, out, ws, B, spt);
}